// Round 3
// 457.336 us; speedup vs baseline: 1.5190x; 1.5190x over previous
//
#include <hip/hip_runtime.h>
#include <math.h>

#define NCH 256
#define HH 100
#define WW 152
#define BB 4
#define NROIS 512
#define FDIM 12544   // 256*49
#define DFC 1024
#define HW 15200     // 100*152

typedef unsigned short u16;
typedef float f32x2 __attribute__((ext_vector_type(2)));
typedef float f32x4 __attribute__((ext_vector_type(4)));
typedef short s16x8 __attribute__((ext_vector_type(8)));
typedef __bf16 bf16x8 __attribute__((ext_vector_type(8)));

__device__ __forceinline__ u16 f2bf(float f) {
  union { float f; unsigned u; } c; c.f = f;
  unsigned u = c.u;
  return (u16)((u + 0x7FFFu + ((u >> 16) & 1u)) >> 16);  // RNE
}
__device__ __forceinline__ float bf2f(u16 h) {
  union { unsigned u; float f; } c; c.u = ((unsigned)h) << 16;
  return c.f;
}

// ---------------- deform roi pool (proven correct, unchanged) ----------
template<int WITH_OFF>
__global__ __launch_bounds__(256) void pool_nchw(
    const float* __restrict__ feat, const float* __restrict__ rois,
    const float* __restrict__ offp, float* __restrict__ out) {
  const int n    = blockIdx.x;
  const int tid  = threadIdx.x;
  const int wave = tid >> 6;
  const int lane = tid & 63;
  float r[5];
  const float* rp = rois + n * 5;
  #pragma unroll
  for (int i = 0; i < 5; ++i) r[i] = rp[i];
  int b = (int)r[0];
  b = min(max(b, 0), BB - 1);
  const float x1 = r[1] * 0.0625f - 0.5f;
  const float y1 = r[2] * 0.0625f - 0.5f;
  const float x2 = r[3] * 0.0625f - 0.5f;
  const float y2 = r[4] * 0.0625f - 0.5f;
  const float rw = x2 - x1, rh = y2 - y1;
  const float bw = rw * (1.0f / 7.0f), bh = rh * (1.0f / 7.0f);
  const int bin = lane;
  const bool active = (bin < 49);
  const int ph = bin / 7;
  const int pw = bin - ph * 7;
  float sw = x1, sh = y1;
  if (WITH_OFF && active) {
    sw += 0.1f * rw * offp[n * 98 + bin];
    sh += 0.1f * rh * offp[n * 98 + 49 + bin];
  }
  int idx[4];
  float wt[4][4];
  bool val[4];
  #pragma unroll
  for (int s = 0; s < 4; ++s) {
    const int i = s >> 1, j = s & 1;
    const float y = sh + ((float)ph + 0.25f + 0.5f * (float)i) * bh;
    const float x = sw + ((float)pw + 0.25f + 0.5f * (float)j) * bw;
    val[s] = active && (y > -1.0f) && (y < (float)HH) && (x > -1.0f) && (x < (float)WW);
    float yc = fminf(fmaxf(y, 0.f), (float)(HH - 1));
    float xc = fminf(fmaxf(x, 0.f), (float)(WW - 1));
    int y0 = min(max((int)floorf(yc), 0), HH - 2);
    int x0 = min(max((int)floorf(xc), 0), WW - 2);
    const float ly = yc - (float)y0, lx = xc - (float)x0;
    const float hy = 1.f - ly, hx = 1.f - lx;
    idx[s] = y0 * WW + x0;
    wt[s][0] = hy * hx; wt[s][1] = hy * lx;
    wt[s][2] = ly * hx; wt[s][3] = ly * lx;
  }
  const float* fb = feat + (size_t)b * NCH * HW;
  float* op = out + (size_t)n * FDIM;
  for (int c = wave; c < NCH; c += 4) {
    const float* plane = fb + (size_t)c * HW;
    float acc = 0.f;
    #pragma unroll
    for (int s = 0; s < 4; ++s) {
      if (val[s]) {
        const float* p = plane + idx[s];
        acc += wt[s][0] * p[0] + wt[s][1] * p[1]
             + wt[s][2] * p[WW] + wt[s][3] * p[WW + 1];
      }
    }
    if (active) op[c * 49 + bin] = acc * 0.25f;
  }
}

// ------------- rescale head (proven correct, unchanged) ----------------
__global__ __launch_bounds__(64) void rescale_rois_kernel(
    const float* __restrict__ flat, const float* __restrict__ w,
    const float* __restrict__ bsc, const float* __restrict__ rois,
    float* __restrict__ new_rois) {
  const int n = blockIdx.x, lane = threadIdx.x;
  const float* a = flat + (size_t)n * FDIM;
  float acc[4] = {0.f, 0.f, 0.f, 0.f};
  for (int k = lane * 8; k + 8 <= FDIM; k += 64 * 8) {
    f32x4 a0 = *(const f32x4*)(a + k);
    f32x4 a1 = *(const f32x4*)(a + k + 4);
    #pragma unroll
    for (int j = 0; j < 4; ++j) {
      f32x4 w0 = *(const f32x4*)(w + (size_t)j * FDIM + k);
      f32x4 w1 = *(const f32x4*)(w + (size_t)j * FDIM + k + 4);
      float s = 0.f;
      #pragma unroll
      for (int e = 0; e < 4; ++e) s += a0[e] * w0[e];
      #pragma unroll
      for (int e = 0; e < 4; ++e) s += a1[e] * w1[e];
      acc[j] += s;
    }
  }
  #pragma unroll
  for (int j = 0; j < 4; ++j)
    #pragma unroll
    for (int d = 32; d > 0; d >>= 1)
      acc[j] += __shfl_down(acc[j], d, 64);
  if (lane == 0) {
    float rr[5];
    const float* rp = rois + n * 5;
    #pragma unroll
    for (int i = 0; i < 5; ++i) rr[i] = rp[i];
    float sc[4];
    #pragma unroll
    for (int j = 0; j < 4; ++j) {
      const float z = acc[j] + bsc[j];
      sc[j] = 1.0f + 0.5f / (1.0f + expf(-z));
    }
    const float cx = (rr[1] + rr[3]) * 0.5f + sc[0];
    const float cy = (rr[2] + rr[4]) * 0.5f + sc[1];
    const float nw = (rr[3] - rr[1]) * sc[2];
    const float nh = (rr[4] - rr[2]) * sc[3];
    float* o = new_rois + n * 5;
    o[0] = rr[0];
    o[1] = cx - 0.5f * nw;
    o[2] = cy - 0.5f * nh;
    o[3] = cx + 0.5f * nw;
    o[4] = cy + 0.5f * nh;
  }
}

// ---- split-K SPLIT-BF16 MFMA NT GEMM partials: part[s] = A·B^T --------
// Round-2 trusted structure (64x64 tile, 4 waves, pitch-40 LDS, D-map:
// col = lane&15 = N, row = (lane>>4)*4+i = M), upgraded to "3xTF32":
// a = ah + al (ah = RNE bf16(a), al = RNE bf16(a-ah), residual ~2^-18 rel),
// acc += ah*bh + al*bh + ah*bl  -> effective rel error ~2^-17 (vs bf16's
// 2^-9), which keeps deform-pool sampling positions within ~2e-5 cells of
// the f32 reference (no validity-boundary flips).
// M mult of 64; grid.x = Ns/64 (Ns mult of 64, >= N; invalid B rows staged
// as zeros); kchunk mult of 32.
__global__ __launch_bounds__(256) void gemm_mfma64_sk(
    const float* __restrict__ A, const float* __restrict__ B,
    float* __restrict__ part, int M, int N, int Ns, int K, int kchunk) {
  __shared__ __align__(16) u16 Ah[64 * 40];
  __shared__ __align__(16) u16 Al[64 * 40];
  __shared__ __align__(16) u16 Bh[64 * 40];
  __shared__ __align__(16) u16 Bl[64 * 40];
  const int tid  = threadIdx.x;
  const int wave = tid >> 6;
  const int lane = tid & 63;
  const int q  = lane >> 4;
  const int rr = lane & 15;
  const int m_base = blockIdx.y * 64;
  const int n_base = blockIdx.x * 64;
  const int s  = blockIdx.z;
  const int kb = s * kchunk, ke = kb + kchunk;
  const int ldr = tid >> 2;
  const int ldc = (tid & 3) << 3;
  f32x4 acc[4];
  #pragma unroll
  for (int i = 0; i < 4; ++i) acc[i] = (f32x4){0.f, 0.f, 0.f, 0.f};
  const size_t a_off = (size_t)(m_base + ldr) * K + ldc;
  const int  brow = n_base + ldr;
  const bool bok  = brow < N;
  const size_t b_off = (size_t)(bok ? brow : 0) * K + ldc;
  for (int k0 = kb; k0 < ke; k0 += 32) {
    s16x8 avh, avl, bvh, bvl;
    {
      f32x4 a0 = *(const f32x4*)(A + a_off + k0);
      f32x4 a1 = *(const f32x4*)(A + a_off + k0 + 4);
      f32x4 b0 = (f32x4){0.f, 0.f, 0.f, 0.f}, b1 = b0;
      if (bok) { b0 = *(const f32x4*)(B + b_off + k0); b1 = *(const f32x4*)(B + b_off + k0 + 4); }
      #pragma unroll
      for (int e = 0; e < 4; ++e) {
        u16 h;
        h = f2bf(a0[e]); avh[e]     = (short)h; avl[e]     = (short)f2bf(a0[e] - bf2f(h));
        h = f2bf(a1[e]); avh[e + 4] = (short)h; avl[e + 4] = (short)f2bf(a1[e] - bf2f(h));
        h = f2bf(b0[e]); bvh[e]     = (short)h; bvl[e]     = (short)f2bf(b0[e] - bf2f(h));
        h = f2bf(b1[e]); bvh[e + 4] = (short)h; bvl[e + 4] = (short)f2bf(b1[e] - bf2f(h));
      }
    }
    *(s16x8*)&Ah[ldr * 40 + ldc] = avh;
    *(s16x8*)&Al[ldr * 40 + ldc] = avl;
    *(s16x8*)&Bh[ldr * 40 + ldc] = bvh;
    *(s16x8*)&Bl[ldr * 40 + ldc] = bvl;
    __syncthreads();
    const bf16x8 bhf = *(const bf16x8*)&Bh[(wave * 16 + rr) * 40 + (q << 3)];
    const bf16x8 blf = *(const bf16x8*)&Bl[(wave * 16 + rr) * 40 + (q << 3)];
    #pragma unroll
    for (int mt = 0; mt < 4; ++mt) {
      const bf16x8 ahf = *(const bf16x8*)&Ah[(mt * 16 + rr) * 40 + (q << 3)];
      const bf16x8 alf = *(const bf16x8*)&Al[(mt * 16 + rr) * 40 + (q << 3)];
      acc[mt] = __builtin_amdgcn_mfma_f32_16x16x32_bf16(ahf, bhf, acc[mt], 0, 0, 0);
      acc[mt] = __builtin_amdgcn_mfma_f32_16x16x32_bf16(alf, bhf, acc[mt], 0, 0, 0);
      acc[mt] = __builtin_amdgcn_mfma_f32_16x16x32_bf16(ahf, blf, acc[mt], 0, 0, 0);
    }
    __syncthreads();
  }
  float* pb = part + (size_t)s * M * Ns;
  const int col = n_base + wave * 16 + rr;
  #pragma unroll
  for (int mt = 0; mt < 4; ++mt) {
    #pragma unroll
    for (int i = 0; i < 4; ++i) {
      const int row = m_base + mt * 16 + (q << 2) + i;
      pb[(size_t)row * Ns + col] = acc[mt][i];
    }
  }
}

// ---- reduce partials + bias (+relu): out[m][n] = f(sum_s part + bias) ----
template<int RELU>
__global__ __launch_bounds__(256) void reduce_sk(
    const float* __restrict__ part, const float* __restrict__ bias,
    float* __restrict__ out, int M, int N, int Ns, int S) {
  const int idx = blockIdx.x * 256 + threadIdx.x;
  if (idx >= M * Ns) return;
  const int m = idx / Ns, n = idx - m * Ns;
  if (n >= N) return;
  float v = bias[n];
  for (int s = 0; s < S; ++s) v += part[(size_t)s * M * Ns + idx];
  if (RELU) v = fmaxf(v, 0.f);
  out[(size_t)m * N + n] = v;
}

extern "C" void kernel_launch(void* const* d_in, const int* in_sizes, int n_in,
                              void* d_out, int out_size, void* d_ws, size_t ws_size,
                              hipStream_t stream) {
  const float* input  = (const float*)d_in[0];
  const float* rois   = (const float*)d_in[1];
  const float* resc_w = (const float*)d_in[2];
  const float* resc_b = (const float*)d_in[3];
  const float* w1     = (const float*)d_in[4];
  const float* b1     = (const float*)d_in[5];
  const float* w2     = (const float*)d_in[6];
  const float* b2     = (const float*)d_in[7];
  const float* w3     = (const float*)d_in[8];
  const float* b3     = (const float*)d_in[9];
  float* out = (float*)d_out;

  // ws layout (unchanged, ~23 MB)
  char* ws = (char*)d_ws;
  float* part   = (float*)ws;                                  // 16 MB (8x512x1024)
  float* h1     = (float*)(ws + (16u << 20));                  // 2 MB
  float* h2     = (float*)(ws + (18u << 20));                  // 2 MB
  float* offbuf = (float*)(ws + (22u << 20));                  // 200 KB
  float* nrois  = (float*)(ws + (22u << 20) + 256 * 1024);     // 10 KB

  float* x_cls = out;
  float* x_reg = out + (size_t)NROIS * FDIM;

  pool_nchw<0><<<NROIS, 256, 0, stream>>>(input, rois, nullptr, x_cls);
  rescale_rois_kernel<<<NROIS, 64, 0, stream>>>(x_cls, resc_w, resc_b, rois, nrois);

  // GEMM1: 512x1024x12544  (kchunk 1568 = 49 k-steps)
  gemm_mfma64_sk<<<dim3(16, 8, 8), 256, 0, stream>>>(x_cls, w1, part, NROIS, DFC, DFC, FDIM, FDIM / 8);
  reduce_sk<1><<<(NROIS * DFC + 255) / 256, 256, 0, stream>>>(part, b1, h1, NROIS, DFC, DFC, 8);
  // GEMM2: 512x1024x1024  (kchunk 128 = 4 k-steps)
  gemm_mfma64_sk<<<dim3(16, 8, 8), 256, 0, stream>>>(h1, w2, part, NROIS, DFC, DFC, DFC, DFC / 8);
  reduce_sk<1><<<(NROIS * DFC + 255) / 256, 256, 0, stream>>>(part, b2, h2, NROIS, DFC, DFC, 8);
  // GEMM3: 512x98x1024 (Ns=128 pad; bx=1 has rows 64..127, rows >=98 zeroed)
  gemm_mfma64_sk<<<dim3(2, 8, 8), 256, 0, stream>>>(h2, w3, part, NROIS, 98, 128, DFC, DFC / 8);
  reduce_sk<0><<<(NROIS * 128 + 255) / 256, 256, 0, stream>>>(part, b3, offbuf, NROIS, 98, 128, 8);

  pool_nchw<1><<<NROIS, 256, 0, stream>>>(input, nrois, offbuf, x_reg);
}

// Round 4
// 432.383 us; speedup vs baseline: 1.6067x; 1.0577x over previous
//
#include <hip/hip_runtime.h>
#include <math.h>

#define NCH 256
#define HH 100
#define WW 152
#define BB 4
#define NROIS 512
#define FDIM 12544   // 256*49
#define DFC 1024
#define HW 15200     // 100*152

typedef unsigned short u16;
typedef float f32x2 __attribute__((ext_vector_type(2)));
typedef float f32x4 __attribute__((ext_vector_type(4)));
typedef short s16x8 __attribute__((ext_vector_type(8)));
typedef __bf16 bf16x8 __attribute__((ext_vector_type(8)));

// ---------------- deform roi pool (proven correct, unchanged) ----------
template<int WITH_OFF>
__global__ __launch_bounds__(256) void pool_nchw(
    const float* __restrict__ feat, const float* __restrict__ rois,
    const float* __restrict__ offp, float* __restrict__ out) {
  const int n    = blockIdx.x;
  const int tid  = threadIdx.x;
  const int wave = tid >> 6;
  const int lane = tid & 63;
  float r[5];
  const float* rp = rois + n * 5;
  #pragma unroll
  for (int i = 0; i < 5; ++i) r[i] = rp[i];
  int b = (int)r[0];
  b = min(max(b, 0), BB - 1);
  const float x1 = r[1] * 0.0625f - 0.5f;
  const float y1 = r[2] * 0.0625f - 0.5f;
  const float x2 = r[3] * 0.0625f - 0.5f;
  const float y2 = r[4] * 0.0625f - 0.5f;
  const float rw = x2 - x1, rh = y2 - y1;
  const float bw = rw * (1.0f / 7.0f), bh = rh * (1.0f / 7.0f);
  const int bin = lane;
  const bool active = (bin < 49);
  const int ph = bin / 7;
  const int pw = bin - ph * 7;
  float sw = x1, sh = y1;
  if (WITH_OFF && active) {
    sw += 0.1f * rw * offp[n * 98 + bin];
    sh += 0.1f * rh * offp[n * 98 + 49 + bin];
  }
  int idx[4];
  float wt[4][4];
  bool val[4];
  #pragma unroll
  for (int s = 0; s < 4; ++s) {
    const int i = s >> 1, j = s & 1;
    const float y = sh + ((float)ph + 0.25f + 0.5f * (float)i) * bh;
    const float x = sw + ((float)pw + 0.25f + 0.5f * (float)j) * bw;
    val[s] = active && (y > -1.0f) && (y < (float)HH) && (x > -1.0f) && (x < (float)WW);
    float yc = fminf(fmaxf(y, 0.f), (float)(HH - 1));
    float xc = fminf(fmaxf(x, 0.f), (float)(WW - 1));
    int y0 = min(max((int)floorf(yc), 0), HH - 2);
    int x0 = min(max((int)floorf(xc), 0), WW - 2);
    const float ly = yc - (float)y0, lx = xc - (float)x0;
    const float hy = 1.f - ly, hx = 1.f - lx;
    idx[s] = y0 * WW + x0;
    wt[s][0] = hy * hx; wt[s][1] = hy * lx;
    wt[s][2] = ly * hx; wt[s][3] = ly * lx;
  }
  const float* fb = feat + (size_t)b * NCH * HW;
  float* op = out + (size_t)n * FDIM;
  for (int c = wave; c < NCH; c += 4) {
    const float* plane = fb + (size_t)c * HW;
    float acc = 0.f;
    #pragma unroll
    for (int s = 0; s < 4; ++s) {
      if (val[s]) {
        const float* p = plane + idx[s];
        acc += wt[s][0] * p[0] + wt[s][1] * p[1]
             + wt[s][2] * p[WW] + wt[s][3] * p[WW + 1];
      }
    }
    if (active) op[c * 49 + bin] = acc * 0.25f;
  }
}

// ------------- rescale head (proven correct, unchanged) ----------------
__global__ __launch_bounds__(64) void rescale_rois_kernel(
    const float* __restrict__ flat, const float* __restrict__ w,
    const float* __restrict__ bsc, const float* __restrict__ rois,
    float* __restrict__ new_rois) {
  const int n = blockIdx.x, lane = threadIdx.x;
  const float* a = flat + (size_t)n * FDIM;
  float acc[4] = {0.f, 0.f, 0.f, 0.f};
  for (int k = lane * 8; k + 8 <= FDIM; k += 64 * 8) {
    f32x4 a0 = *(const f32x4*)(a + k);
    f32x4 a1 = *(const f32x4*)(a + k + 4);
    #pragma unroll
    for (int j = 0; j < 4; ++j) {
      f32x4 w0 = *(const f32x4*)(w + (size_t)j * FDIM + k);
      f32x4 w1 = *(const f32x4*)(w + (size_t)j * FDIM + k + 4);
      float s = 0.f;
      #pragma unroll
      for (int e = 0; e < 4; ++e) s += a0[e] * w0[e];
      #pragma unroll
      for (int e = 0; e < 4; ++e) s += a1[e] * w1[e];
      acc[j] += s;
    }
  }
  #pragma unroll
  for (int j = 0; j < 4; ++j)
    #pragma unroll
    for (int d = 32; d > 0; d >>= 1)
      acc[j] += __shfl_down(acc[j], d, 64);
  if (lane == 0) {
    float rr[5];
    const float* rp = rois + n * 5;
    #pragma unroll
    for (int i = 0; i < 5; ++i) rr[i] = rp[i];
    float sc[4];
    #pragma unroll
    for (int j = 0; j < 4; ++j) {
      const float z = acc[j] + bsc[j];
      sc[j] = 1.0f + 0.5f / (1.0f + expf(-z));
    }
    const float cx = (rr[1] + rr[3]) * 0.5f + sc[0];
    const float cy = (rr[2] + rr[4]) * 0.5f + sc[1];
    const float nw = (rr[3] - rr[1]) * sc[2];
    const float nh = (rr[4] - rr[2]) * sc[3];
    float* o = new_rois + n * 5;
    o[0] = rr[0];
    o[1] = cx - 0.5f * nw;
    o[2] = cy - 0.5f * nh;
    o[3] = cx + 0.5f * nw;
    o[4] = cy + 0.5f * nh;
  }
}

// ---- split-K SPLIT-BF16 MFMA NT GEMM partials: part[s] = A·B^T --------
// 64(M) x 128(N) x BK=32 tile, 512 threads = 8 waves (2M x 4N), wave tile
// 32x32 (2x2 fragments x 3 MFMA: ah*bh + al*bh + ah*bl). Splits use
// compiler (__bf16) RNE casts (bit-identical to round-3's hand f2bf,
// proven by round-1/round-2 bit-equality; compiler emits cvt_pk pairs).
// LDS XOR swizzle (write slot^((row>>1)&3) / read q^((rr>>1)&3), row
// bases 16-aligned) spreads every ds_{read,write}_b128 evenly over all
// 32 banks. D-map (trusted): col = lane&15 = N, row = (lane>>4)*4+i = M.
// M mult of 64; grid.x = Ns/128 (Ns mult of 128, >= N; invalid B rows
// staged as zeros); kchunk mult of 32.
__global__ __launch_bounds__(512, 4) void gemm_mfma_sk(
    const float* __restrict__ A, const float* __restrict__ B,
    float* __restrict__ part, int M, int N, int Ns, int K, int kchunk) {
  __shared__ __align__(16) u16 Ah[64 * 32];
  __shared__ __align__(16) u16 Al[64 * 32];
  __shared__ __align__(16) u16 Bh[128 * 32];
  __shared__ __align__(16) u16 Bl[128 * 32];
  const int tid  = threadIdx.x;
  const int wave = tid >> 6;
  const int lane = tid & 63;
  const int q  = lane >> 4;
  const int rr = lane & 15;
  const int wr = wave >> 2;        // 0..1 : M wave row (32 rows each)
  const int wc = wave & 3;         // 0..3 : N wave col (32 cols each)
  const int m0 = blockIdx.y * 64;
  const int n0 = blockIdx.x * 128;
  const int s  = blockIdx.z;
  const int kb = s * kchunk, ke = kb + kchunk;

  // staging: B rows 0..127 by all 512 threads; A rows 0..63 by tids<256
  const int srow  = tid >> 2;
  const int sslot = tid & 3;
  const int swz   = sslot ^ ((srow >> 1) & 3);
  const bool astage = tid < 256;
  u16* const a_sth = &Ah[srow * 32 + swz * 8];
  u16* const a_stl = &Al[srow * 32 + swz * 8];
  u16* const b_sth = &Bh[srow * 32 + swz * 8];
  u16* const b_stl = &Bl[srow * 32 + swz * 8];
  const float* Ap = A + (size_t)(m0 + (astage ? srow : 0)) * K + sslot * 8;
  const int  brow = n0 + srow;
  const bool bok  = brow < N;
  const float* Bp = B + (size_t)(bok ? brow : 0) * K + sslot * 8;

  // fragment reads (row bases 16-aligned -> (row>>1)&3 == (rr>>1)&3)
  const int rsw = q ^ ((rr >> 1) & 3);
  const u16* const a_rdh = &Ah[(wr * 32 + rr) * 32 + rsw * 8];
  const u16* const a_rdl = &Al[(wr * 32 + rr) * 32 + rsw * 8];
  const u16* const b_rdh = &Bh[(wc * 32 + rr) * 32 + rsw * 8];
  const u16* const b_rdl = &Bl[(wc * 32 + rr) * 32 + rsw * 8];

  f32x4 acc[2][2];
  #pragma unroll
  for (int mt = 0; mt < 2; ++mt)
    #pragma unroll
    for (int nt = 0; nt < 2; ++nt) acc[mt][nt] = (f32x4){0.f, 0.f, 0.f, 0.f};

  for (int k0 = kb; k0 < ke; k0 += 32) {
    f32x4 a0 = (f32x4){0.f, 0.f, 0.f, 0.f}, a1 = a0, b0 = a0, b1 = a0;
    if (astage) { a0 = *(const f32x4*)(Ap + k0); a1 = *(const f32x4*)(Ap + k0 + 4); }
    if (bok)    { b0 = *(const f32x4*)(Bp + k0); b1 = *(const f32x4*)(Bp + k0 + 4); }
    bf16x8 avh, avl, bvh, bvl;
    #pragma unroll
    for (int e = 0; e < 4; ++e) {
      const __bf16 h0 = (__bf16)a0[e], h1 = (__bf16)a1[e];
      avh[e] = h0; avh[e + 4] = h1;
      avl[e]     = (__bf16)(a0[e] - (float)h0);
      avl[e + 4] = (__bf16)(a1[e] - (float)h1);
      const __bf16 g0 = (__bf16)b0[e], g1 = (__bf16)b1[e];
      bvh[e] = g0; bvh[e + 4] = g1;
      bvl[e]     = (__bf16)(b0[e] - (float)g0);
      bvl[e + 4] = (__bf16)(b1[e] - (float)g1);
    }
    __syncthreads();             // previous tile fully consumed
    if (astage) { *(bf16x8*)a_sth = avh; *(bf16x8*)a_stl = avl; }
    *(bf16x8*)b_sth = bvh;
    *(bf16x8*)b_stl = bvl;
    __syncthreads();
    bf16x8 ah[2], al[2], bh[2], bl[2];
    #pragma unroll
    for (int mt = 0; mt < 2; ++mt) {
      ah[mt] = *(const bf16x8*)(a_rdh + mt * 16 * 32);
      al[mt] = *(const bf16x8*)(a_rdl + mt * 16 * 32);
    }
    #pragma unroll
    for (int nt = 0; nt < 2; ++nt) {
      bh[nt] = *(const bf16x8*)(b_rdh + nt * 16 * 32);
      bl[nt] = *(const bf16x8*)(b_rdl + nt * 16 * 32);
    }
    #pragma unroll
    for (int mt = 0; mt < 2; ++mt)
      #pragma unroll
      for (int nt = 0; nt < 2; ++nt) {
        acc[mt][nt] = __builtin_amdgcn_mfma_f32_16x16x32_bf16(ah[mt], bh[nt], acc[mt][nt], 0, 0, 0);
        acc[mt][nt] = __builtin_amdgcn_mfma_f32_16x16x32_bf16(al[mt], bh[nt], acc[mt][nt], 0, 0, 0);
        acc[mt][nt] = __builtin_amdgcn_mfma_f32_16x16x32_bf16(ah[mt], bl[nt], acc[mt][nt], 0, 0, 0);
      }
  }

  float* pb = part + (size_t)s * M * Ns;
  #pragma unroll
  for (int mt = 0; mt < 2; ++mt)
    #pragma unroll
    for (int nt = 0; nt < 2; ++nt) {
      const int col = n0 + wc * 32 + nt * 16 + rr;
      #pragma unroll
      for (int i = 0; i < 4; ++i) {
        const int row = m0 + wr * 32 + mt * 16 + q * 4 + i;
        pb[(size_t)row * Ns + col] = acc[mt][nt][i];
      }
    }
}

// ---- reduce partials + bias (+relu): out[m][n] = f(sum_s part + bias) ----
template<int RELU>
__global__ __launch_bounds__(256) void reduce_sk(
    const float* __restrict__ part, const float* __restrict__ bias,
    float* __restrict__ out, int M, int N, int Ns, int S) {
  const int idx = blockIdx.x * 256 + threadIdx.x;
  if (idx >= M * Ns) return;
  const int m = idx / Ns, n = idx - m * Ns;
  if (n >= N) return;
  float v = bias[n];
  for (int s = 0; s < S; ++s) v += part[(size_t)s * M * Ns + idx];
  if (RELU) v = fmaxf(v, 0.f);
  out[(size_t)m * N + n] = v;
}

extern "C" void kernel_launch(void* const* d_in, const int* in_sizes, int n_in,
                              void* d_out, int out_size, void* d_ws, size_t ws_size,
                              hipStream_t stream) {
  const float* input  = (const float*)d_in[0];
  const float* rois   = (const float*)d_in[1];
  const float* resc_w = (const float*)d_in[2];
  const float* resc_b = (const float*)d_in[3];
  const float* w1     = (const float*)d_in[4];
  const float* b1     = (const float*)d_in[5];
  const float* w2     = (const float*)d_in[6];
  const float* b2     = (const float*)d_in[7];
  const float* w3     = (const float*)d_in[8];
  const float* b3     = (const float*)d_in[9];
  float* out = (float*)d_out;

  // ws layout (unchanged, ~23 MB)
  char* ws = (char*)d_ws;
  float* part   = (float*)ws;                                  // 16 MB (8x512x1024)
  float* h1     = (float*)(ws + (16u << 20));                  // 2 MB
  float* h2     = (float*)(ws + (18u << 20));                  // 2 MB
  float* offbuf = (float*)(ws + (22u << 20));                  // 200 KB
  float* nrois  = (float*)(ws + (22u << 20) + 256 * 1024);     // 10 KB

  float* x_cls = out;
  float* x_reg = out + (size_t)NROIS * FDIM;

  pool_nchw<0><<<NROIS, 256, 0, stream>>>(input, rois, nullptr, x_cls);
  rescale_rois_kernel<<<NROIS, 64, 0, stream>>>(x_cls, resc_w, resc_b, rois, nrois);

  // GEMM1: 512x1024x12544  (kchunk 1568 = 49 k-steps)
  gemm_mfma_sk<<<dim3(8, 8, 8), 512, 0, stream>>>(x_cls, w1, part, NROIS, DFC, DFC, FDIM, FDIM / 8);
  reduce_sk<1><<<(NROIS * DFC + 255) / 256, 256, 0, stream>>>(part, b1, h1, NROIS, DFC, DFC, 8);
  // GEMM2: 512x1024x1024  (kchunk 128 = 4 k-steps)
  gemm_mfma_sk<<<dim3(8, 8, 8), 512, 0, stream>>>(h1, w2, part, NROIS, DFC, DFC, DFC, DFC / 8);
  reduce_sk<1><<<(NROIS * DFC + 255) / 256, 256, 0, stream>>>(part, b2, h2, NROIS, DFC, DFC, 8);
  // GEMM3: 512x98x1024 (Ns=128 pad; B rows >= 98 staged as zeros)
  gemm_mfma_sk<<<dim3(1, 8, 8), 512, 0, stream>>>(h2, w3, part, NROIS, 98, 128, DFC, DFC / 8);
  reduce_sk<0><<<(NROIS * 128 + 255) / 256, 256, 0, stream>>>(part, b3, offbuf, NROIS, 98, 128, 8);

  pool_nchw<1><<<NROIS, 256, 0, stream>>>(input, nrois, offbuf, x_reg);
}